// Round 1
// 812.268 us; speedup vs baseline: 1.1709x; 1.1709x over previous
//
#include <hip/hip_runtime.h>
#include <stdint.h>

typedef unsigned int uint32;

#define B 8
#define N 25600
#define DMSG 128
#define DNODE 256
#define NBINS 200
#define PBIN 128
#define NR 100          // rotation columns used (n_bins/2)
#define NKEY 400        // bin_idx range: 0..398
#define CH 256          // sort chunk size
#define NCHUNK 100      // N / CH
#define EPS 1e-6f
#define DISTM 0.1f

typedef short short8 __attribute__((ext_vector_type(8)));
typedef float floatx4 __attribute__((ext_vector_type(4)));

__device__ __forceinline__ unsigned short f2bf(float f) {
    uint32 u = __float_as_uint(f);
    u += 0x7fffu + ((u >> 16) & 1u);   // RNE (lossless here: inputs are bf16-rounded)
    return (unsigned short)(u >> 16);
}

// ---------------------------------------------------------------------------
// K1: LSH projection + argmax binning + per-chunk histogram.
// NEW: fp32 filter + fp64 verify. Single pass over K with all 100 fp32
// accumulators in VGPRs (X staged to LDS once, 4 phases instead of 16).
// The fp32 argmax is certified when the top-2 gap exceeds THRESH; THRESH
// is >=6x the rigorous fp32-fma error bound (128 terms, |partial| <= 210:
// e <= 128*210*2^-24 ~ 1.6e-3, need > 2e). Near-ties (~0.5% of points)
// recompute ONLY candidate columns in fp64 with the same serial-k fma
// order as the previous (passing) all-fp64 kernel -> identical binning.
// ---------------------------------------------------------------------------
__global__ __launch_bounds__(256, 2) void k_bin(const float* __restrict__ xmsg,
                                                const int* __restrict__ msk,
                                                const float* __restrict__ rot,
                                                int* __restrict__ binidx,
                                                int* __restrict__ counts) {
    __shared__ float Xs[CH][36];   // row stride 144B: float4-aligned
    __shared__ int hist[NKEY];
    const int tid = threadIdx.x;
    const int b = blockIdx.x / NCHUNK;
    const int chunk = blockIdx.x % NCHUNK;
    const int pbase = b * N + chunk * CH;

    float acc[NR];
#pragma unroll
    for (int j = 0; j < NR; j++) acc[j] = 0.f;

#pragma unroll 1
    for (int kc = 0; kc < 4; kc++) {
        __syncthreads();
#pragma unroll
        for (int i = 0; i < 8; i++) {
            int s = i * 256 + tid;
            int p = s >> 3, q = s & 7;
            float4 v = *(const float4*)(xmsg + (long)(pbase + p) * DMSG + kc * 32 + q * 4);
            *(float4*)&Xs[p][q * 4] = v;
        }
        __syncthreads();
#pragma unroll 1
        for (int k4 = 0; k4 < 8; k4++) {
            float4 xv = *(const float4*)&Xs[tid][k4 * 4];
#pragma unroll
            for (int c = 0; c < 4; c++) {
                const float xk = (c == 0) ? xv.x : (c == 1) ? xv.y : (c == 2) ? xv.z : xv.w;
                const float* __restrict__ rrow = rot + (kc * 32 + k4 * 4 + c) * NR;
                // chunks of 25 keep the scalar rot loads SGPR-comfortable
#pragma unroll
                for (int jc = 0; jc < 4; jc++)
#pragma unroll
                    for (int j = 0; j < 25; j++)
                        acc[jc * 25 + j] = fmaf(xk, rrow[jc * 25 + j], acc[jc * 25 + j]);
            }
        }
    }

    // top-2 over the 200 virtual columns (concat(+acc, -acc)); strict >
    // keeps the earliest index (stable argmax, matches jnp.argmax)
    float m1 = -1e30f, m2 = -1e30f;
    int i1 = 0;
#pragma unroll
    for (int j = 0; j < NR; j++) {
        const float a = acc[j];
        if (a > m1) { m2 = m1; m1 = a; i1 = j; }
        else if (a > m2) { m2 = a; }
    }
#pragma unroll
    for (int j = 0; j < NR; j++) {
        const float a = -acc[j];
        if (a > m1) { m2 = m1; m1 = a; i1 = NR + j; }
        else if (a > m2) { m2 = a; }
    }
    int bj = i1;

    const float THRESH = 0.02f;   // >> 2*e_fp32 (~3.2e-3): certified if gap larger
    if (m1 - m2 < THRESH) {
        // candidate mask built with STATIC indices (acc stays in VGPRs)
        const float cut = m1 - THRESH;
        unsigned long long cm0 = 0ull, cm1 = 0ull;
#pragma unroll
        for (int j = 0; j < 64; j++)
            cm0 |= ((unsigned long long)(fmaxf(acc[j], -acc[j]) >= cut)) << j;
#pragma unroll
        for (int j = 64; j < NR; j++)
            cm1 |= ((unsigned long long)(fmaxf(acc[j], -acc[j]) >= cut)) << (j - 64);

        const float* __restrict__ xrow = xmsg + (long)(pbase + tid) * DMSG;
        double bestp = -1e300, bestn = -1e300;
        int bjp = 0, bjn = 0;
        while (cm0 | cm1) {
            int j;
            if (cm0) { j = __ffsll(cm0) - 1; cm0 &= cm0 - 1; }
            else     { j = 64 + __ffsll(cm1) - 1; cm1 &= cm1 - 1; }
            // serial-k fp64 fma: same accumulation order as previous kernel
            double s = 0.0;
            for (int k = 0; k < DMSG; k++)
                s = fma((double)xrow[k], (double)rot[k * NR + j], s);
            if (s > bestp)  { bestp = s;  bjp = j; }
            if (-s > bestn) { bestn = -s; bjn = j; }
        }
        bj = (bestp >= bestn) ? bjp : NR + bjn;
    }

    const int m = msk[pbase + tid];
    const int bin = bj + (m ? 0 : (NBINS - 1));
    binidx[pbase + tid] = bin;

    for (int i = tid; i < NKEY; i += 256) hist[i] = 0;
    __syncthreads();
    atomicAdd(&hist[bin], 1);
    __syncthreads();
    for (int i = tid; i < NKEY; i += 256)
        counts[(b * NKEY + i) * NCHUNK + chunk] = hist[i];
}

// ---------------------------------------------------------------------------
// K2: per-batch exclusive prefix sum over counts (bin-major, chunk-minor).
// ---------------------------------------------------------------------------
__global__ void k_scan(int* __restrict__ counts) {
    const int b = blockIdx.x;
    const int base = b * (NKEY * NCHUNK);
    const int tot = NKEY * NCHUNK;          // 40000
    const int seg = (tot + 255) / 256;      // 157
    const int tid = threadIdx.x;
    const int lo = tid * seg;
    const int hi = min(lo + seg, tot);
    int s = 0;
    for (int i = lo; i < hi; i++) s += counts[base + i];
    __shared__ int sums[256];
    sums[tid] = s;
    __syncthreads();
    if (tid == 0) {
        int run = 0;
        for (int i = 0; i < 256; i++) { int t = sums[i]; sums[i] = run; run += t; }
    }
    __syncthreads();
    int run = sums[tid];
    for (int i = lo; i < hi; i++) { int t = counts[base + i]; counts[base + i] = run; run += t; }
}

// ---------------------------------------------------------------------------
// K3: stable scatter -> perm (ws) and bins_split (out0, fp32 ints).
// ---------------------------------------------------------------------------
__global__ void k_scatter(const int* __restrict__ binidx, const int* __restrict__ counts,
                          int* __restrict__ perm, float* __restrict__ out0) {
    __shared__ int bins[CH];
    const int tid = threadIdx.x;
    const int b = blockIdx.x / NCHUNK;
    const int chunk = blockIdx.x % NCHUNK;
    const int n = chunk * CH + tid;
    const int bin = binidx[b * N + n];
    bins[tid] = bin;
    __syncthreads();
    int r = 0;
    for (int i = 0; i < CH; i++) {
        if (i < tid && bins[i] == bin) r++;
    }
    const int pos = counts[(b * NKEY + bin) * NCHUNK + chunk] + r;
    perm[b * N + pos] = n;
    out0[b * N + pos] = (float)n;
}

// ---------------------------------------------------------------------------
// K4: gather x_node rows (1KB read + 1KB write per row, one wave per row).
// ---------------------------------------------------------------------------
__global__ void k_gather(const float* __restrict__ xnode, const int* __restrict__ msk,
                         const int* __restrict__ perm, float* __restrict__ out1,
                         float* __restrict__ out3) {
    const int tid = threadIdx.x;
    const int wid = tid >> 6, lane = tid & 63;
    const int row = blockIdx.x * 4 + wid;   // < B*N
    const int b = row / N, pos = row % N;
    const int src = perm[b * N + pos];
    const float4* s4 = (const float4*)(xnode + (long)(b * N + src) * DNODE);
    float4* d4 = (float4*)(out1 + (long)row * DNODE);
    d4[lane] = s4[lane];
    if (lane == 0) out3[row] = msk[b * N + src] ? 1.0f : 0.0f;
}

// ---------------------------------------------------------------------------
// K5: per-bin Gaussian kernel. bf16 staging is LOSSLESS (inputs bf16-rounded),
// gram via mfma_f32_16x16x32_bf16, diag forced to EPS, fp32 epilogue stores.
// ---------------------------------------------------------------------------
__global__ void k_dm(const float* __restrict__ xmsg, const int* __restrict__ msk,
                     const int* __restrict__ perm, float* __restrict__ out2) {
    __shared__ unsigned short Xbf[PBIN][136];  // row 272B: 16B aligned
    __shared__ float ssq[256];
    __shared__ float sq[PBIN];
    __shared__ float mm[PBIN];
    const int tid = threadIdx.x;
    const int b = blockIdx.x / NBINS;
    const int bin = blockIdx.x % NBINS;

    const int row = tid >> 1, half = tid & 1;
    const int src = perm[b * N + bin * PBIN + row];
    const float mf = msk[b * N + src] ? 1.0f : 0.0f;
    if (half == 0) mm[row] = mf;
    const float4* xp = (const float4*)(xmsg + (long)(b * N + src) * DMSG + half * 64);
    float ss = 0.f;
#pragma unroll
    for (int i = 0; i < 16; i++) {
        float4 v = xp[i];
        v.x *= mf; v.y *= mf; v.z *= mf; v.w *= mf;
        ss += v.x * v.x + v.y * v.y + v.z * v.z + v.w * v.w;
        uint2 pk;
        pk.x = (uint32)f2bf(v.x) | ((uint32)f2bf(v.y) << 16);
        pk.y = (uint32)f2bf(v.z) | ((uint32)f2bf(v.w) << 16);
        *(uint2*)&Xbf[row][half * 64 + i * 4] = pk;
    }
    ssq[tid] = ss;
    __syncthreads();
    if (tid < PBIN) sq[tid] = ssq[2 * tid] + ssq[2 * tid + 1];
    __syncthreads();

    const int w = tid >> 6, lane = tid & 63;
    const int lrow = lane & 15, quad = lane >> 4;

    short8 af[2][4];
#pragma unroll
    for (int t = 0; t < 2; t++) {
        int rr = (w * 2 + t) * 16 + lrow;
#pragma unroll
        for (int kk = 0; kk < 4; kk++)
            af[t][kk] = *(const short8*)&Xbf[rr][kk * 32 + quad * 8];
    }

    const long obase = (long)(b * NBINS + bin) * (PBIN * PBIN);
#pragma unroll 1
    for (int tc = 0; tc < 8; tc++) {
        const int cc = tc * 16 + lrow;
        short8 bf[4];
#pragma unroll
        for (int kk = 0; kk < 4; kk++)
            bf[kk] = *(const short8*)&Xbf[cc][kk * 32 + quad * 8];
        const float sqc = sq[cc];
        const float mc = mm[cc];
#pragma unroll
        for (int t = 0; t < 2; t++) {
            floatx4 acc = {0.f, 0.f, 0.f, 0.f};
#pragma unroll
            for (int kk = 0; kk < 4; kk++)
                acc = __builtin_amdgcn_mfma_f32_16x16x32_bf16(af[t][kk], bf[kk], acc, 0, 0, 0);
            const int rbase = (w * 2 + t) * 16 + quad * 4;
#pragma unroll
            for (int i = 0; i < 4; i++) {
                int rr = rbase + i;
                float val = sq[rr] + sqc - 2.f * acc[i];
                val = (rr == cc) ? EPS : fmaxf(val, EPS);
                float d = sqrtf(val);
                float e = fminf(__expf(-DISTM * d), 1.0f);
                out2[obase + (long)rr * PBIN + cc] = e * mm[rr] * mc;
            }
        }
    }
}

// ---------------------------------------------------------------------------
extern "C" void kernel_launch(void* const* d_in, const int* in_sizes, int n_in,
                              void* d_out, int out_size, void* d_ws, size_t ws_size,
                              hipStream_t stream) {
    const float* xmsg  = (const float*)d_in[0];
    const float* xnode = (const float*)d_in[1];
    const int*   msk   = (const int*)d_in[2];
    const float* rot   = (const float*)d_in[3];

    int* ws = (int*)d_ws;
    int* binidx = ws;                                // B*N
    int* counts = ws + B * N;                        // B*NKEY*NCHUNK
    int* perm   = ws + B * N + B * NKEY * NCHUNK;    // B*N

    float* out0 = (float*)d_out;                               // bins_split (fp32 ints)
    float* out1 = out0 + (long)B * N;                          // x_node_b
    float* out2 = out1 + (long)B * N * DNODE;                  // dm
    float* out3 = out2 + (long)B * NBINS * PBIN * PBIN;        // msk_b

    k_bin<<<B * NCHUNK, 256, 0, stream>>>(xmsg, msk, rot, binidx, counts);
    k_scan<<<B, 256, 0, stream>>>(counts);
    k_scatter<<<B * NCHUNK, 256, 0, stream>>>(binidx, counts, perm, out0);
    k_gather<<<(B * N) / 4, 256, 0, stream>>>(xnode, msk, perm, out1, out3);
    k_dm<<<B * NBINS, 256, 0, stream>>>(xmsg, msk, perm, out2);
}